// Round 8
// baseline (339.917 us; speedup 1.0000x reference)
//
#include <hip/hip_runtime.h>

// Problem constants (MultiScaleRetention: B=4, L=4096, D=1024, H=16, DH=64)
#define BB 4
#define LL 4096
#define DM 1024
#define NH 16
#define MM (BB * LL)   // 16384 rows
#define CC2 256        // scan chunks per sequence
#define LC2 16         // chunk length (CC2*LC2 == LL)

// GEMM geometry: 256x256 tile, BK=64, 8 waves (2Mx4N), 1-barrier-per-tile
// counted-lgkm interleave schedule.
#define BKT 64
#define NKT (DM / BKT)   // 16 K-tiles

typedef unsigned short u16;
typedef float f32x4 __attribute__((ext_vector_type(4)));
typedef int i32x4 __attribute__((ext_vector_type(4)));
typedef __bf16 mfma_in __attribute__((ext_vector_type(8)));

__device__ __forceinline__ u16 f2bf(float f) {
    unsigned u = __float_as_uint(f);
    u += 0x7FFFu + ((u >> 16) & 1u);   // RNE
    return (u16)(u >> 16);
}
__device__ __forceinline__ float bf2f(u16 u) {
    return __uint_as_float(((unsigned)u) << 16);
}

// async global->LDS, 16B per lane; LDS dest = wave-uniform base + lane*16
__device__ __forceinline__ void gld_lds16(const u16* g, u16* l) {
    __builtin_amdgcn_global_load_lds(
        (const __attribute__((address_space(1))) void*)g,
        (__attribute__((address_space(3))) void*)l,
        16, 0, 0);
}

// Inline-asm ds_read_b128: invisible to the compiler's waitcnt tracking, so
// no hidden vmcnt(0)/lgkmcnt(0) drains get inserted. Completion is enforced
// by our explicit counted lgkmcnt + sched_barrier(0) (DS ops complete
// in-order per wave, so counted waits are deterministic).
__device__ __forceinline__ mfma_in ds_read128(const u16* p) {
    i32x4 r;
    unsigned off = (unsigned)(size_t)(const __attribute__((address_space(3))) u16*)p;
    asm volatile("ds_read_b128 %0, %1" : "=v"(r) : "v"(off));
    return __builtin_bit_cast(mfma_in, r);
}

// ---------------------------------------------------------------- conversions
#define XF4 (MM * DM / 4)
#define WF4 (DM * DM / 4)
__global__ __launch_bounds__(256)
void cvt_all(const float* __restrict__ x,
             const float* __restrict__ w0, const float* __restrict__ w1,
             const float* __restrict__ w2, const float* __restrict__ w3,
             u16* __restrict__ dst) {
    int i = blockIdx.x * 256 + threadIdx.x;
    const float* src;
    int si;
    if (i < XF4) { src = x; si = i; }
    else {
        int j = i - XF4;
        int w = j >> 18;            // WF4 == 2^18
        si = j & (WF4 - 1);
        src = (w == 0) ? w0 : (w == 1) ? w1 : (w == 2) ? w2 : w3;
    }
    float4 f = ((const float4*)src)[si];
    ushort4 o;
    o.x = f2bf(f.x); o.y = f2bf(f.y); o.z = f2bf(f.z); o.w = f2bf(f.w);
    ((ushort4*)dst)[i] = o;
}

// ---------------------------------------------------------------- 256^2 GEMM
// LDS layout per 256x64 K-tile buffer: row = 64 u16 (8 chunks of 16B),
// chunk at (row, logical c) stored at phys = c ^ (row&7) (XOR bank swizzle).
// Staging: swizzle pre-folded into the GLOBAL source address (linear LDS dest).
// Fragment read: row r, k-step s, logical chunk 4s+quad -> phys (4s+quad)^(r&7).
//
// r4/r5 lesson: mfma(b,a) operand swap + vectorized epilogue added ~11us of
// pure pipe-idle -> stay on the r3 config: mfma(a,b), scalar-store epilogue,
// split staging (A at tile start, B at ~60%).
// r8: XCD-aware block swizzle (FETCH 78MB -> ~45-55MB expected: blocks
// sharing a B panel now land on one XCD's L2) + skip the dead kt=15 stage.
//
// Tile schedule (1 barrier/tile, counted lgkm interleave; DS in-order/wave):
//   issue G1 aLs0(4) G2 bLs0(2) G3 aHs0(4) | stage A(k+1) 4x gld
//   lgkm(4)  -> Q0s0   (G1,G2 done; G3<=4 out)
//   issue G4 bHs0(2); lgkm(2) -> Q1s0      (G3 done; G4<=2)
//   issue G5 aLs1(4); lgkm(4) -> Q2s0,Q3s0 (G4 done; G5<=4)
//   issue G6 bLs1(2) G7 aHs1(4) | stage B(k+1) 4x gld
//   lgkm(4)  -> Q0s1   (G5,G6 done; G7<=4)
//   issue G8 bHs1(2); lgkm(2) -> Q1s1      (G7 done; G8<=2)
//   lgkm(0)  -> Q2s1,Q3s1
//   vmcnt(0); s_barrier      // staged tile k+1 landed+visible; WAR safe

template<int IOFF, int JOFF>
__device__ __forceinline__ void mfma8(const mfma_in (&a)[4], const mfma_in (&b)[2],
                                      f32x4 (&acc)[8][4]) {
#pragma unroll
    for (int i = 0; i < 4; i++)
#pragma unroll
        for (int j = 0; j < 2; j++)
            acc[IOFF + i][JOFF + j] = __builtin_amdgcn_mfma_f32_16x16x32_bf16(
                a[i], b[j], acc[IOFF + i][JOFF + j], 0, 0, 0);
}

#define WAITL(n) do { \
    asm volatile("s_waitcnt lgkmcnt(" #n ")"); \
    __builtin_amdgcn_sched_barrier(0); \
} while (0)

__device__ __forceinline__ void mainloop256(
    const u16* __restrict__ A, const u16* __restrict__ B,
    int mBlk, int nBlk,
    u16 (*__restrict__ As)[256 * 64], u16 (*__restrict__ Bs)[256 * 64],
    f32x4 (&acc)[8][4]) {
    const int tid  = threadIdx.x;
    const int wave = tid >> 6;
    const int lane = tid & 63;
    const int quad = lane >> 4;
    const int l16  = lane & 15;
    const int wm   = (wave >> 2) * 128;   // wave-row: 0..1 -> A half
    const int wn   = (wave & 3) * 64;     // wave-col: 0..3

    // staging addressing (swizzle folded into global source)
    const int sRow = wave * 8 + (lane >> 3);
    const int sCol = ((lane & 7) ^ (lane >> 3)) * 8;
    const u16* gA = A + (size_t)(mBlk + sRow) * DM + sCol;
    const u16* gB = B + (size_t)(nBlk + sRow) * DM + sCol;
    const int ldsW = wave * 8 * 64;       // wave's element offset within a 64-row segment

    // fragment read offsets
    int rA[8], rB[4];
#pragma unroll
    for (int i = 0; i < 8; i++) rA[i] = (wm + i * 16 + l16) * 64;
#pragma unroll
    for (int j = 0; j < 4; j++) rB[j] = (wn + j * 16 + l16) * 64;
    const int c0 = ((quad    ) ^ (l16 & 7)) * 8;
    const int c1 = ((quad + 4) ^ (l16 & 7)) * 8;

    // stage one full 256x64 tile (4x gld_lds per wave), rows in 64-row segments
#define STG4_A(dst, t) do { \
    const int kk_ = (t) * BKT; \
    gld_lds16(gA + kk_,                   (dst) + ldsW); \
    gld_lds16(gA + (size_t) 64 * DM + kk_, (dst) +  64 * 64 + ldsW); \
    gld_lds16(gA + (size_t)128 * DM + kk_, (dst) + 128 * 64 + ldsW); \
    gld_lds16(gA + (size_t)192 * DM + kk_, (dst) + 192 * 64 + ldsW); \
} while (0)
#define STG4_B(dst, t) do { \
    const int kk_ = (t) * BKT; \
    gld_lds16(gB + kk_,                   (dst) + ldsW); \
    gld_lds16(gB + (size_t) 64 * DM + kk_, (dst) +  64 * 64 + ldsW); \
    gld_lds16(gB + (size_t)128 * DM + kk_, (dst) + 128 * 64 + ldsW); \
    gld_lds16(gB + (size_t)192 * DM + kk_, (dst) + 192 * 64 + ldsW); \
} while (0)
#define RDA(dst, idx, cc) (dst) = ds_read128(curA + rA[idx] + (cc))
#define RDB(dst, idx, cc) (dst) = ds_read128(curB + rB[idx] + (cc))

    mfma_in aLs0[4], aHs0[4], bLs0[2], bHs0[2];
    mfma_in aLs1[4], aHs1[4], bLs1[2], bHs1[2];

    // prologue: stage tile 0 into buf0, drain, publish
    STG4_A(As[0], 0);
    STG4_B(Bs[0], 0);
    asm volatile("s_waitcnt vmcnt(0)");
    __builtin_amdgcn_s_barrier();

#pragma unroll 1
    for (int kt = 0; kt < NKT; ++kt) {
        const int cur = kt & 1, nxt = cur ^ 1;
        const u16* curA = As[cur];
        const u16* curB = Bs[cur];
        const bool pre = (kt + 1 < NKT);   // no dead stage on the last tile

        // G1 aL s0, G2 bL s0, G3 aH s0  (out=10)
#pragma unroll
        for (int i = 0; i < 4; i++) RDA(aLs0[i], i, c0);
#pragma unroll
        for (int j = 0; j < 2; j++) RDB(bLs0[j], j, c0);
#pragma unroll
        for (int i = 0; i < 4; i++) RDA(aHs0[i], i + 4, c0);
        if (pre) STG4_A(As[nxt], kt + 1);
        __builtin_amdgcn_sched_barrier(0);

        WAITL(4);                      // G1,G2 done
        __builtin_amdgcn_s_setprio(1);
        mfma8<0, 0>(aLs0, bLs0, acc);  // Q0s0
        __builtin_amdgcn_s_setprio(0);

#pragma unroll
        for (int j = 0; j < 2; j++) RDB(bHs0[j], j + 2, c0);   // G4 (out<=6)
        WAITL(2);                      // G3 done
        __builtin_amdgcn_s_setprio(1);
        mfma8<4, 0>(aHs0, bLs0, acc);  // Q1s0
        __builtin_amdgcn_s_setprio(0);

#pragma unroll
        for (int i = 0; i < 4; i++) RDA(aLs1[i], i, c1);       // G5 (out<=6)
        WAITL(4);                      // G4 done
        __builtin_amdgcn_s_setprio(1);
        mfma8<0, 2>(aLs0, bHs0, acc);  // Q2s0
        mfma8<4, 2>(aHs0, bHs0, acc);  // Q3s0
        __builtin_amdgcn_s_setprio(0);

#pragma unroll
        for (int j = 0; j < 2; j++) RDB(bLs1[j], j, c1);       // G6
#pragma unroll
        for (int i = 0; i < 4; i++) RDA(aHs1[i], i + 4, c1);   // G7 (out<=10)
        if (pre) STG4_B(Bs[nxt], kt + 1);
        __builtin_amdgcn_sched_barrier(0);

        WAITL(4);                      // G5,G6 done
        __builtin_amdgcn_s_setprio(1);
        mfma8<0, 0>(aLs1, bLs1, acc);  // Q0s1
        __builtin_amdgcn_s_setprio(0);

#pragma unroll
        for (int j = 0; j < 2; j++) RDB(bHs1[j], j + 2, c1);   // G8 (out<=6)
        WAITL(2);                      // G7 done
        __builtin_amdgcn_s_setprio(1);
        mfma8<4, 0>(aHs1, bLs1, acc);  // Q1s1
        __builtin_amdgcn_s_setprio(0);

        WAITL(0);                      // G8 done; all tile-k reads drained
        __builtin_amdgcn_s_setprio(1);
        mfma8<0, 2>(aLs1, bHs1, acc);  // Q2s1
        mfma8<4, 2>(aHs1, bHs1, acc);  // Q3s1
        __builtin_amdgcn_s_setprio(0);

        // publish tile k+1 (RAW) + protect bufs for next tile's stages (WAR)
        __builtin_amdgcn_sched_barrier(0);
        asm volatile("s_waitcnt vmcnt(0)");
        __builtin_amdgcn_sched_barrier(0);
        __builtin_amdgcn_s_barrier();
    }
#undef STG4_A
#undef STG4_B
#undef RDA
#undef RDB
}

// fused q/v/g projection: B = concatenated 3072x1024 weights; 3 bf16 outputs.
// v-region blocks also emit retention chunk-ends (ebuf) from the f32 accs.
// XCD-aware block swizzle: nwg = 64*12 = 768 = 8*96 (exactly divisible) ->
// swz = (id%8)*96 + id/8 gives each XCD a contiguous chunk of 96 ids, so the
// ~64 blocks sharing one B panel land on 1-2 XCDs instead of all 8.
__global__ __launch_bounds__(512, 2)
void gemm_qvg(const u16* __restrict__ A, const u16* __restrict__ B,
              u16* __restrict__ oq, u16* __restrict__ ov, u16* __restrict__ og,
              const float* __restrict__ beta, float* __restrict__ ebuf) {
    __shared__ __align__(16) u16 As[2][256 * 64];
    __shared__ __align__(16) u16 Bs[2][256 * 64];
    const int id  = blockIdx.y * gridDim.x + blockIdx.x;   // 0..767
    const int swz = (id & 7) * 96 + (id >> 3);             // bijective (768 = 8*96)
    const int mBlk = (swz & 63) * 256;                     // 64 m-blocks (fast)
    const int nBlk = (swz >> 6) * 256;                     // 12 n-blocks

    f32x4 acc[8][4] = {};
    mainloop256(A, B, mBlk, nBlk, As, Bs, acc);

    const int tid  = threadIdx.x;
    const int wave = tid >> 6;
    const int lane = tid & 63;
    const int quad = lane >> 4;
    const int l16  = lane & 15;
    const int wm   = (wave >> 2) * 128;
    const int wn   = (wave & 3) * 64;

    u16* outs[3] = {oq, ov, og};
    u16* O = outs[nBlk >> 10];
    const int nIn = nBlk & 1023;
#pragma unroll
    for (int i = 0; i < 8; i++) {
        int row0 = mBlk + wm + i * 16 + quad * 4;
#pragma unroll
        for (int j = 0; j < 4; j++) {
            int col = nIn + wn + j * 16 + l16;
#pragma unroll
            for (int r = 0; r < 4; r++)
                O[(size_t)(row0 + r) * DM + col] = f2bf(acc[i][j][r]);
        }
    }

    if ((nBlk >> 10) == 1) {
        // fused chunk-ends for the v region (f32-accurate, pre-bf16-rounding)
        const int rowB = mBlk + wm;            // 256-row tile never straddles a seq
        const int b    = rowB >> 12;
        const int cB   = (rowB & 4095) >> 4;   // chunk of i=0
#pragma unroll
        for (int j = 0; j < 4; j++) {
            int col = nIn + wn + j * 16 + l16; // head uniform across l16 (base%16==0)
            float lam  = 1.0f / (1.0f + __expf(-beta[col >> 6]));
            float lam2 = lam * lam, lam4 = lam2 * lam2, lam8 = lam4 * lam4;
            float w = quad == 0 ? lam4 * lam8 : quad == 1 ? lam8
                    : quad == 2 ? lam4 : 1.0f;
#pragma unroll
            for (int i = 0; i < 8; i++) {
                f32x4 a = acc[i][j];
                float p = ((a[0] * lam + a[1]) * lam + a[2]) * lam + a[3];
                float v = p * w;
                v += __shfl_xor(v, 16);
                v += __shfl_xor(v, 32);
                if (quad == 0)
                    ebuf[((size_t)b * CC2 + (cB + i)) * DM + col] = v;
            }
        }
    }
}

// output projection: C (f32) = A @ B^T.  nwg = 64*4 = 256 = 8*32.
__global__ __launch_bounds__(512, 2)
void gemm_out(const u16* __restrict__ A, const u16* __restrict__ B,
              float* __restrict__ C) {
    __shared__ __align__(16) u16 As[2][256 * 64];
    __shared__ __align__(16) u16 Bs[2][256 * 64];
    const int id  = blockIdx.y * gridDim.x + blockIdx.x;   // 0..255
    const int swz = (id & 7) * 32 + (id >> 3);             // bijective (256 = 8*32)
    const int mBlk = (swz & 63) * 256;
    const int nBlk = (swz >> 6) * 256;

    f32x4 acc[8][4] = {};
    mainloop256(A, B, mBlk, nBlk, As, Bs, acc);

    const int tid  = threadIdx.x;
    const int wave = tid >> 6;
    const int lane = tid & 63;
    const int quad = lane >> 4;
    const int l16  = lane & 15;
    const int wm   = (wave >> 2) * 128;
    const int wn   = (wave & 3) * 64;

#pragma unroll
    for (int i = 0; i < 8; i++) {
        int row0 = mBlk + wm + i * 16 + quad * 4;
#pragma unroll
        for (int j = 0; j < 4; j++) {
            int col = nBlk + wn + j * 16 + l16;
#pragma unroll
            for (int r = 0; r < 4; r++)
                C[(size_t)(row0 + r) * DM + col] = acc[i][j][r];
        }
    }
}

// ---------------------------------------------------------------- scan phase B
__global__ __launch_bounds__(256)
void scan_carry(const float* __restrict__ ebuf, const float* __restrict__ beta,
                float* __restrict__ carry) {
    int ch = blockIdx.x * 256 + threadIdx.x;  // 0..BB*DM-1
    int b = ch >> 10, d = ch & 1023;
    int h = d >> 6;
    float lam = 1.0f / (1.0f + __expf(-beta[h]));
    float lamC = lam;
    for (int i = 0; i < 4; i++) lamC *= lamC;  // lam^16
    float cur = 0.0f;
#pragma unroll 8
    for (int c = 0; c < CC2; c++) {
        size_t idx = ((size_t)b * CC2 + c) * DM + d;
        carry[idx] = cur;
        cur = lamC * cur + ebuf[idx];
    }
}

// ---------------------------------------------------------------- scan phase C:
// seeded re-scan + y=q*state + LayerNorm + SiLU gate -> bf16
__global__ __launch_bounds__(256)
void scan_ln_gate(const u16* __restrict__ v, const u16* __restrict__ q,
                  const u16* __restrict__ g, const float* __restrict__ carry,
                  const float* __restrict__ beta, const float* __restrict__ gamma,
                  const float* __restrict__ lnb, u16* __restrict__ out) {
    __shared__ float red[2][8];
    const int t = threadIdx.x;
    const int c = blockIdx.x, b = blockIdx.y;
    const int wave = t >> 6, lane = t & 63;
    const int d0 = t * 4;
    const int h = d0 >> 6;
    float lam = 1.0f / (1.0f + __expf(-beta[h]));
    float4 gm = ((const float4*)gamma)[t];
    float4 bt = ((const float4*)lnb)[t];
    float4 cr = *(const float4*)(carry + ((size_t)b * CC2 + c) * DM + d0);
    float s0 = cr.x, s1 = cr.y, s2 = cr.z, s3 = cr.w;
    size_t base = ((size_t)b * LL + (size_t)c * LC2) * DM + d0;

    for (int i = 0; i < LC2; i++) {
        ushort4 v4 = *(const ushort4*)(v + base);
        ushort4 q4 = *(const ushort4*)(q + base);
        ushort4 g4 = *(const ushort4*)(g + base);
        s0 = lam * s0 + bf2f(v4.x);
        s1 = lam * s1 + bf2f(v4.y);
        s2 = lam * s2 + bf2f(v4.z);
        s3 = lam * s3 + bf2f(v4.w);
        float y0 = bf2f(q4.x) * s0, y1 = bf2f(q4.y) * s1;
        float y2 = bf2f(q4.z) * s2, y3 = bf2f(q4.w) * s3;
        float sum = y0 + y1 + y2 + y3;
        float sq  = y0 * y0 + y1 * y1 + y2 * y2 + y3 * y3;
#pragma unroll
        for (int off = 32; off > 0; off >>= 1) {
            sum += __shfl_xor(sum, off);
            sq  += __shfl_xor(sq, off);
        }
        int p = i & 1;
        if (lane == 0) { red[p][wave] = sum; red[p][4 + wave] = sq; }
        __syncthreads();
        float ts = red[p][0] + red[p][1] + red[p][2] + red[p][3];
        float tq = red[p][4] + red[p][5] + red[p][6] + red[p][7];
        float mu  = ts * (1.0f / DM);
        float inv = rsqrtf(tq * (1.0f / DM) - mu * mu + 1e-5f);

        float gv0 = bf2f(g4.x), gv1 = bf2f(g4.y), gv2 = bf2f(g4.z), gv3 = bf2f(g4.w);
        float x0 = ((y0 - mu) * inv * gm.x + bt.x) * (gv0 / (1.0f + __expf(-gv0)));
        float x1 = ((y1 - mu) * inv * gm.y + bt.y) * (gv1 / (1.0f + __expf(-gv1)));
        float x2 = ((y2 - mu) * inv * gm.z + bt.z) * (gv2 / (1.0f + __expf(-gv2)));
        float x3 = ((y3 - mu) * inv * gm.w + bt.w) * (gv3 / (1.0f + __expf(-gv3)));
        ushort4 o;
        o.x = f2bf(x0); o.y = f2bf(x1); o.z = f2bf(x2); o.w = f2bf(x3);
        *(ushort4*)(out + base) = o;
        base += DM;
    }
}

// ---------------------------------------------------------------- launcher
extern "C" void kernel_launch(void* const* d_in, const int* in_sizes, int n_in,
                              void* d_out, int out_size, void* d_ws, size_t ws_size,
                              hipStream_t stream) {
    const float* x     = (const float*)d_in[0];
    const float* Wq    = (const float*)d_in[1];
    const float* Wv    = (const float*)d_in[2];
    const float* Wg    = (const float*)d_in[3];
    const float* Wo    = (const float*)d_in[4];
    const float* beta  = (const float*)d_in[5];
    const float* gamma = (const float*)d_in[6];
    const float* lnb   = (const float*)d_in[7];

    // workspace layout (bf16 elements) — xb..Wob contiguous for cvt_all
    u16* xb  = (u16*)d_ws;                    // reused as y_final
    u16* Wqb = xb + (size_t)MM * DM;          // Wq,Wv,Wg concat = 3072x1024
    u16* Wob = Wqb + (size_t)3 * DM * DM;
    u16* qb  = Wob + (size_t)DM * DM;
    u16* vb  = qb + (size_t)MM * DM;
    u16* gb  = vb + (size_t)MM * DM;
    float* ebuf  = (float*)(gb + (size_t)MM * DM);   // BB*CC2*DM f32
    float* carry = ebuf + (size_t)BB * CC2 * DM;
    u16* yfin = xb;

    // 1) fp32 -> bf16, single launch
    cvt_all<<<(XF4 + 4 * WF4 + 255) / 256, 256, 0, stream>>>(x, Wq, Wv, Wg, Wo, xb);

    // 2) fused q/v/g projection (N=3072 concat) + chunk-ends for v
    dim3 gq(MM / 256, 3 * DM / 256);
    gemm_qvg<<<gq, 512, 0, stream>>>(xb, Wqb, qb, vb, gb, beta, ebuf);

    // 3) retention scan carries + fused LN + SiLU gate
    scan_carry<<<(BB * DM) / 256, 256, 0, stream>>>(ebuf, beta, carry);
    dim3 gf(CC2, BB);
    scan_ln_gate<<<gf, 256, 0, stream>>>(vb, qb, gb, carry, beta, gamma, lnb, yfin);

    // 4) output projection (fp32 out)
    dim3 go(MM / 256, DM / 256);
    gemm_out<<<go, 512, 0, stream>>>(yfin, Wob, (float*)d_out);
}

// Round 10
// 322.366 us; speedup vs baseline: 1.0544x; 1.0544x over previous
//
#include <hip/hip_runtime.h>

// Problem constants (MultiScaleRetention: B=4, L=4096, D=1024, H=16, DH=64)
#define BB 4
#define LL 4096
#define DM 1024
#define NH 16
#define MM (BB * LL)   // 16384 rows
#define CC2 256        // scan chunks per sequence
#define LC2 16         // chunk length (CC2*LC2 == LL)

// GEMM geometry: 256x256 tile, BK=64, 8 waves (2Mx4N), 1-barrier-per-tile
// counted-lgkm interleave schedule.  (r9 pipe-split crashed: ~250 live regs
// vs 256 cap -> spill -> scratch ops break counted vmcnt. Reverted to r6.)
#define BKT 64
#define NKT (DM / BKT)   // 16 K-tiles

typedef unsigned short u16;
typedef float f32x4 __attribute__((ext_vector_type(4)));
typedef int i32x4 __attribute__((ext_vector_type(4)));
typedef __bf16 mfma_in __attribute__((ext_vector_type(8)));

__device__ __forceinline__ u16 f2bf(float f) {
    unsigned u = __float_as_uint(f);
    u += 0x7FFFu + ((u >> 16) & 1u);   // RNE
    return (u16)(u >> 16);
}
__device__ __forceinline__ float bf2f(u16 u) {
    return __uint_as_float(((unsigned)u) << 16);
}

// async global->LDS, 16B per lane; LDS dest = wave-uniform base + lane*16
__device__ __forceinline__ void gld_lds16(const u16* g, u16* l) {
    __builtin_amdgcn_global_load_lds(
        (const __attribute__((address_space(1))) void*)g,
        (__attribute__((address_space(3))) void*)l,
        16, 0, 0);
}

// Inline-asm ds_read_b128: invisible to the compiler's waitcnt tracking, so
// no hidden vmcnt(0)/lgkmcnt(0) drains get inserted. Completion is enforced
// by our explicit counted lgkmcnt + sched_barrier(0) (DS ops complete
// in-order per wave, so counted waits are deterministic).
__device__ __forceinline__ mfma_in ds_read128(const u16* p) {
    i32x4 r;
    unsigned off = (unsigned)(size_t)(const __attribute__((address_space(3))) u16*)p;
    asm volatile("ds_read_b128 %0, %1" : "=v"(r) : "v"(off));
    return __builtin_bit_cast(mfma_in, r);
}

// ---------------------------------------------------------------- conversions
#define XF4 (MM * DM / 4)
#define WF4 (DM * DM / 4)
__global__ __launch_bounds__(256)
void cvt_all(const float* __restrict__ x,
             const float* __restrict__ w0, const float* __restrict__ w1,
             const float* __restrict__ w2, const float* __restrict__ w3,
             u16* __restrict__ dst) {
    int i = blockIdx.x * 256 + threadIdx.x;
    const float* src;
    int si;
    if (i < XF4) { src = x; si = i; }
    else {
        int j = i - XF4;
        int w = j >> 18;            // WF4 == 2^18
        si = j & (WF4 - 1);
        src = (w == 0) ? w0 : (w == 1) ? w1 : (w == 2) ? w2 : w3;
    }
    float4 f = ((const float4*)src)[si];
    ushort4 o;
    o.x = f2bf(f.x); o.y = f2bf(f.y); o.z = f2bf(f.z); o.w = f2bf(f.w);
    ((ushort4*)dst)[i] = o;
}

// ---------------------------------------------------------------- 256^2 GEMM
// LDS layout per 256x64 K-tile buffer: row = 64 u16 (8 chunks of 16B),
// chunk at (row, logical c) stored at phys = c ^ (row&7) (XOR bank swizzle).
// Staging: swizzle pre-folded into the GLOBAL source address (linear LDS dest).
// Fragment read: row r, k-step s, logical chunk 4s+quad -> phys (4s+quad)^(r&7).
//
// Proven r6 config: mfma(a,b), scalar-store epilogue, split staging (A at
// tile start, B at ~60%), linear block mapping (r8 swizzle destroyed L2
// temporal locality: FETCH 78->203 MB).
//
// Tile schedule (1 barrier/tile, counted lgkm interleave; DS in-order/wave):
//   issue G1 aLs0(4) G2 bLs0(2) G3 aHs0(4) | stage A(k+1) 4x gld
//   lgkm(4)  -> Q0s0   (G1,G2 done; G3<=4 out)
//   issue G4 bHs0(2); lgkm(2) -> Q1s0      (G3 done; G4<=2)
//   issue G5 aLs1(4); lgkm(4) -> Q2s0,Q3s0 (G4 done; G5<=4)
//   issue G6 bLs1(2) G7 aHs1(4) | stage B(k+1) 4x gld
//   lgkm(4)  -> Q0s1   (G5,G6 done; G7<=4)
//   issue G8 bHs1(2); lgkm(2) -> Q1s1      (G7 done; G8<=2)
//   lgkm(0)  -> Q2s1,Q3s1
//   vmcnt(0); s_barrier      // staged tile k+1 landed+visible; WAR safe

template<int IOFF, int JOFF>
__device__ __forceinline__ void mfma8(const mfma_in (&a)[4], const mfma_in (&b)[2],
                                      f32x4 (&acc)[8][4]) {
#pragma unroll
    for (int i = 0; i < 4; i++)
#pragma unroll
        for (int j = 0; j < 2; j++)
            acc[IOFF + i][JOFF + j] = __builtin_amdgcn_mfma_f32_16x16x32_bf16(
                a[i], b[j], acc[IOFF + i][JOFF + j], 0, 0, 0);
}

#define WAITL(n) do { \
    asm volatile("s_waitcnt lgkmcnt(" #n ")"); \
    __builtin_amdgcn_sched_barrier(0); \
} while (0)

__device__ __forceinline__ void mainloop256(
    const u16* __restrict__ A, const u16* __restrict__ B,
    int mBlk, int nBlk,
    u16 (*__restrict__ As)[256 * 64], u16 (*__restrict__ Bs)[256 * 64],
    f32x4 (&acc)[8][4]) {
    const int tid  = threadIdx.x;
    const int wave = tid >> 6;
    const int lane = tid & 63;
    const int quad = lane >> 4;
    const int l16  = lane & 15;
    const int wm   = (wave >> 2) * 128;   // wave-row: 0..1 -> A half
    const int wn   = (wave & 3) * 64;     // wave-col: 0..3

    // staging addressing (swizzle folded into global source)
    const int sRow = wave * 8 + (lane >> 3);
    const int sCol = ((lane & 7) ^ (lane >> 3)) * 8;
    const u16* gA = A + (size_t)(mBlk + sRow) * DM + sCol;
    const u16* gB = B + (size_t)(nBlk + sRow) * DM + sCol;
    const int ldsW = wave * 8 * 64;       // wave's element offset within a 64-row segment

    // fragment read offsets
    int rA[8], rB[4];
#pragma unroll
    for (int i = 0; i < 8; i++) rA[i] = (wm + i * 16 + l16) * 64;
#pragma unroll
    for (int j = 0; j < 4; j++) rB[j] = (wn + j * 16 + l16) * 64;
    const int c0 = ((quad    ) ^ (l16 & 7)) * 8;
    const int c1 = ((quad + 4) ^ (l16 & 7)) * 8;

    // stage one full 256x64 tile (4x gld_lds per wave), rows in 64-row segments
#define STG4_A(dst, t) do { \
    const int kk_ = (t) * BKT; \
    gld_lds16(gA + kk_,                    (dst) + ldsW); \
    gld_lds16(gA + (size_t) 64 * DM + kk_, (dst) +  64 * 64 + ldsW); \
    gld_lds16(gA + (size_t)128 * DM + kk_, (dst) + 128 * 64 + ldsW); \
    gld_lds16(gA + (size_t)192 * DM + kk_, (dst) + 192 * 64 + ldsW); \
} while (0)
#define STG4_B(dst, t) do { \
    const int kk_ = (t) * BKT; \
    gld_lds16(gB + kk_,                    (dst) + ldsW); \
    gld_lds16(gB + (size_t) 64 * DM + kk_, (dst) +  64 * 64 + ldsW); \
    gld_lds16(gB + (size_t)128 * DM + kk_, (dst) + 128 * 64 + ldsW); \
    gld_lds16(gB + (size_t)192 * DM + kk_, (dst) + 192 * 64 + ldsW); \
} while (0)
#define RDA(dst, idx, cc) (dst) = ds_read128(curA + rA[idx] + (cc))
#define RDB(dst, idx, cc) (dst) = ds_read128(curB + rB[idx] + (cc))

    mfma_in aLs0[4], aHs0[4], bLs0[2], bHs0[2];
    mfma_in aLs1[4], aHs1[4], bLs1[2], bHs1[2];

    // prologue: stage tile 0 into buf0, drain, publish
    STG4_A(As[0], 0);
    STG4_B(Bs[0], 0);
    asm volatile("s_waitcnt vmcnt(0)");
    __builtin_amdgcn_s_barrier();

#pragma unroll 1
    for (int kt = 0; kt < NKT; ++kt) {
        const int cur = kt & 1, nxt = cur ^ 1;
        const u16* curA = As[cur];
        const u16* curB = Bs[cur];
        const bool pre = (kt + 1 < NKT);   // no dead stage on the last tile

        // G1 aL s0, G2 bL s0, G3 aH s0  (out=10)
#pragma unroll
        for (int i = 0; i < 4; i++) RDA(aLs0[i], i, c0);
#pragma unroll
        for (int j = 0; j < 2; j++) RDB(bLs0[j], j, c0);
#pragma unroll
        for (int i = 0; i < 4; i++) RDA(aHs0[i], i + 4, c0);
        if (pre) STG4_A(As[nxt], kt + 1);
        __builtin_amdgcn_sched_barrier(0);

        WAITL(4);                      // G1,G2 done
        __builtin_amdgcn_s_setprio(1);
        mfma8<0, 0>(aLs0, bLs0, acc);  // Q0s0
        __builtin_amdgcn_s_setprio(0);

#pragma unroll
        for (int j = 0; j < 2; j++) RDB(bHs0[j], j + 2, c0);   // G4 (out<=6)
        WAITL(2);                      // G3 done
        __builtin_amdgcn_s_setprio(1);
        mfma8<4, 0>(aHs0, bLs0, acc);  // Q1s0
        __builtin_amdgcn_s_setprio(0);

#pragma unroll
        for (int i = 0; i < 4; i++) RDA(aLs1[i], i, c1);       // G5 (out<=6)
        WAITL(4);                      // G4 done
        __builtin_amdgcn_s_setprio(1);
        mfma8<0, 2>(aLs0, bHs0, acc);  // Q2s0
        mfma8<4, 2>(aHs0, bHs0, acc);  // Q3s0
        __builtin_amdgcn_s_setprio(0);

#pragma unroll
        for (int j = 0; j < 2; j++) RDB(bLs1[j], j, c1);       // G6
#pragma unroll
        for (int i = 0; i < 4; i++) RDA(aHs1[i], i + 4, c1);   // G7 (out<=10)
        if (pre) STG4_B(Bs[nxt], kt + 1);
        __builtin_amdgcn_sched_barrier(0);

        WAITL(4);                      // G5,G6 done
        __builtin_amdgcn_s_setprio(1);
        mfma8<0, 0>(aLs1, bLs1, acc);  // Q0s1
        __builtin_amdgcn_s_setprio(0);

#pragma unroll
        for (int j = 0; j < 2; j++) RDB(bHs1[j], j + 2, c1);   // G8 (out<=6)
        WAITL(2);                      // G7 done
        __builtin_amdgcn_s_setprio(1);
        mfma8<4, 0>(aHs1, bLs1, acc);  // Q1s1
        __builtin_amdgcn_s_setprio(0);

        WAITL(0);                      // G8 done; all tile-k reads drained
        __builtin_amdgcn_s_setprio(1);
        mfma8<0, 2>(aLs1, bHs1, acc);  // Q2s1
        mfma8<4, 2>(aHs1, bHs1, acc);  // Q3s1
        __builtin_amdgcn_s_setprio(0);

        // publish tile k+1 (RAW) + protect bufs for next tile's stages (WAR)
        __builtin_amdgcn_sched_barrier(0);
        asm volatile("s_waitcnt vmcnt(0)");
        __builtin_amdgcn_sched_barrier(0);
        __builtin_amdgcn_s_barrier();
    }
#undef STG4_A
#undef STG4_B
#undef RDA
#undef RDB
}

// fused q/v/g projection: B = concatenated 3072x1024 weights; 3 bf16 outputs.
// v-region blocks also emit retention chunk-ends (ebuf) from the f32 accs.
__global__ __launch_bounds__(512, 2)
void gemm_qvg(const u16* __restrict__ A, const u16* __restrict__ B,
              u16* __restrict__ oq, u16* __restrict__ ov, u16* __restrict__ og,
              const float* __restrict__ beta, float* __restrict__ ebuf) {
    __shared__ __align__(16) u16 As[2][256 * 64];
    __shared__ __align__(16) u16 Bs[2][256 * 64];
    const int mBlk = blockIdx.x * 256;     // linear mapping
    const int nBlk = blockIdx.y * 256;

    f32x4 acc[8][4] = {};
    mainloop256(A, B, mBlk, nBlk, As, Bs, acc);

    const int tid  = threadIdx.x;
    const int wave = tid >> 6;
    const int lane = tid & 63;
    const int quad = lane >> 4;
    const int l16  = lane & 15;
    const int wm   = (wave >> 2) * 128;
    const int wn   = (wave & 3) * 64;

    u16* outs[3] = {oq, ov, og};
    u16* O = outs[nBlk >> 10];
    const int nIn = nBlk & 1023;
#pragma unroll
    for (int i = 0; i < 8; i++) {
        int row0 = mBlk + wm + i * 16 + quad * 4;
#pragma unroll
        for (int j = 0; j < 4; j++) {
            int col = nIn + wn + j * 16 + l16;
#pragma unroll
            for (int r = 0; r < 4; r++)
                O[(size_t)(row0 + r) * DM + col] = f2bf(acc[i][j][r]);
        }
    }

    if ((nBlk >> 10) == 1) {
        // fused chunk-ends for the v region (f32-accurate, pre-bf16-rounding)
        const int rowB = mBlk + wm;            // 256-row tile never straddles a seq
        const int b    = rowB >> 12;
        const int cB   = (rowB & 4095) >> 4;   // chunk of i=0
#pragma unroll
        for (int j = 0; j < 4; j++) {
            int col = nIn + wn + j * 16 + l16;
            float lam  = 1.0f / (1.0f + __expf(-beta[col >> 6]));
            float lam2 = lam * lam, lam4 = lam2 * lam2, lam8 = lam4 * lam4;
            float w = quad == 0 ? lam4 * lam8 : quad == 1 ? lam8
                    : quad == 2 ? lam4 : 1.0f;
#pragma unroll
            for (int i = 0; i < 8; i++) {
                f32x4 a = acc[i][j];
                float p = ((a[0] * lam + a[1]) * lam + a[2]) * lam + a[3];
                float v = p * w;
                v += __shfl_xor(v, 16);
                v += __shfl_xor(v, 32);
                if (quad == 0)
                    ebuf[((size_t)b * CC2 + (cB + i)) * DM + col] = v;
            }
        }
    }
}

// output projection: C (f32) = A @ B^T
__global__ __launch_bounds__(512, 2)
void gemm_out(const u16* __restrict__ A, const u16* __restrict__ B,
              float* __restrict__ C) {
    __shared__ __align__(16) u16 As[2][256 * 64];
    __shared__ __align__(16) u16 Bs[2][256 * 64];
    const int mBlk = blockIdx.x * 256;
    const int nBlk = blockIdx.y * 256;

    f32x4 acc[8][4] = {};
    mainloop256(A, B, mBlk, nBlk, As, Bs, acc);

    const int tid  = threadIdx.x;
    const int wave = tid >> 6;
    const int lane = tid & 63;
    const int quad = lane >> 4;
    const int l16  = lane & 15;
    const int wm   = (wave >> 2) * 128;
    const int wn   = (wave & 3) * 64;

#pragma unroll
    for (int i = 0; i < 8; i++) {
        int row0 = mBlk + wm + i * 16 + quad * 4;
#pragma unroll
        for (int j = 0; j < 4; j++) {
            int col = nBlk + wn + j * 16 + l16;
#pragma unroll
            for (int r = 0; r < 4; r++)
                C[(size_t)(row0 + r) * DM + col] = acc[i][j][r];
        }
    }
}

// ---------------------------------------------------------------- scan phase B
__global__ __launch_bounds__(256)
void scan_carry(const float* __restrict__ ebuf, const float* __restrict__ beta,
                float* __restrict__ carry) {
    int ch = blockIdx.x * 256 + threadIdx.x;  // 0..BB*DM-1
    int b = ch >> 10, d = ch & 1023;
    int h = d >> 6;
    float lam = 1.0f / (1.0f + __expf(-beta[h]));
    float lamC = lam;
    for (int i = 0; i < 4; i++) lamC *= lamC;  // lam^16
    float cur = 0.0f;
#pragma unroll 8
    for (int c = 0; c < CC2; c++) {
        size_t idx = ((size_t)b * CC2 + c) * DM + d;
        carry[idx] = cur;
        cur = lamC * cur + ebuf[idx];
    }
}

// ---------------------------------------------------------------- scan phase C:
// seeded re-scan + y=q*state + LayerNorm + SiLU gate -> bf16.
// BARRIER-FREE rewrite (r10): one WAVE per chunk; lane owns 16 consecutive
// columns, so the scan state is lane-local and the per-row 1024-wide LN
// reduction is 6x shfl_xor only — no __syncthreads, no LDS. Wave reads
// 2KB contiguous per array per row (fully coalesced).
__global__ __launch_bounds__(256)
void scan_ln_gate(const u16* __restrict__ v, const u16* __restrict__ q,
                  const u16* __restrict__ g, const float* __restrict__ carry,
                  const float* __restrict__ beta, const float* __restrict__ gamma,
                  const float* __restrict__ lnb, u16* __restrict__ out) {
    const int t = threadIdx.x;
    const int wave = t >> 6, lane = t & 63;
    const int c = blockIdx.x * 4 + wave;    // chunk index (4 waves = 4 chunks)
    const int b = blockIdx.y;
    const int d0 = lane * 16;               // columns [d0, d0+16)
    float lam = 1.0f / (1.0f + __expf(-beta[d0 >> 6]));   // 16 cols within one head

    float s[16], gm[16], bt[16];
    {
        const float4* cp = (const float4*)(carry + ((size_t)b * CC2 + c) * DM + d0);
        const float4* gp = (const float4*)(gamma + d0);
        const float4* bp = (const float4*)(lnb + d0);
#pragma unroll
        for (int k = 0; k < 4; k++) {
            float4 cv = cp[k], gv = gp[k], bv = bp[k];
            s[4*k+0] = cv.x; s[4*k+1] = cv.y; s[4*k+2] = cv.z; s[4*k+3] = cv.w;
            gm[4*k+0] = gv.x; gm[4*k+1] = gv.y; gm[4*k+2] = gv.z; gm[4*k+3] = gv.w;
            bt[4*k+0] = bv.x; bt[4*k+1] = bv.y; bt[4*k+2] = bv.z; bt[4*k+3] = bv.w;
        }
    }

    size_t base = ((size_t)b * LL + (size_t)c * LC2) * DM + d0;
#pragma unroll 1
    for (int i = 0; i < LC2; i++) {
        float y[16];
        float sum = 0.0f, sq = 0.0f;
#pragma unroll
        for (int k = 0; k < 4; k++) {
            ushort4 vv = ((const ushort4*)(v + base))[k];
            ushort4 qq = ((const ushort4*)(q + base))[k];
            float s0 = (s[4*k+0] = lam * s[4*k+0] + bf2f(vv.x));
            float s1 = (s[4*k+1] = lam * s[4*k+1] + bf2f(vv.y));
            float s2 = (s[4*k+2] = lam * s[4*k+2] + bf2f(vv.z));
            float s3 = (s[4*k+3] = lam * s[4*k+3] + bf2f(vv.w));
            float y0 = bf2f(qq.x) * s0, y1 = bf2f(qq.y) * s1;
            float y2 = bf2f(qq.z) * s2, y3 = bf2f(qq.w) * s3;
            y[4*k+0] = y0; y[4*k+1] = y1; y[4*k+2] = y2; y[4*k+3] = y3;
            sum += (y0 + y1) + (y2 + y3);
            sq  += (y0 * y0 + y1 * y1) + (y2 * y2 + y3 * y3);
        }
#pragma unroll
        for (int off = 32; off > 0; off >>= 1) {
            sum += __shfl_xor(sum, off);
            sq  += __shfl_xor(sq, off);
        }
        float mu  = sum * (1.0f / DM);
        float inv = rsqrtf(sq * (1.0f / DM) - mu * mu + 1e-5f);
#pragma unroll
        for (int k = 0; k < 4; k++) {
            ushort4 gg = ((const ushort4*)(g + base))[k];
            float g0 = bf2f(gg.x), g1 = bf2f(gg.y), g2 = bf2f(gg.z), g3 = bf2f(gg.w);
            ushort4 o;
            o.x = f2bf(((y[4*k+0] - mu) * inv * gm[4*k+0] + bt[4*k+0]) * (g0 / (1.0f + __expf(-g0))));
            o.y = f2bf(((y[4*k+1] - mu) * inv * gm[4*k+1] + bt[4*k+1]) * (g1 / (1.0f + __expf(-g1))));
            o.z = f2bf(((y[4*k+2] - mu) * inv * gm[4*k+2] + bt[4*k+2]) * (g2 / (1.0f + __expf(-g2))));
            o.w = f2bf(((y[4*k+3] - mu) * inv * gm[4*k+3] + bt[4*k+3]) * (g3 / (1.0f + __expf(-g3))));
            ((ushort4*)(out + base))[k] = o;
        }
        base += DM;
    }
}

// ---------------------------------------------------------------- launcher
extern "C" void kernel_launch(void* const* d_in, const int* in_sizes, int n_in,
                              void* d_out, int out_size, void* d_ws, size_t ws_size,
                              hipStream_t stream) {
    const float* x     = (const float*)d_in[0];
    const float* Wq    = (const float*)d_in[1];
    const float* Wv    = (const float*)d_in[2];
    const float* Wg    = (const float*)d_in[3];
    const float* Wo    = (const float*)d_in[4];
    const float* beta  = (const float*)d_in[5];
    const float* gamma = (const float*)d_in[6];
    const float* lnb   = (const float*)d_in[7];

    // workspace layout (bf16 elements) — xb..Wob contiguous for cvt_all
    u16* xb  = (u16*)d_ws;                    // reused as y_final
    u16* Wqb = xb + (size_t)MM * DM;          // Wq,Wv,Wg concat = 3072x1024
    u16* Wob = Wqb + (size_t)3 * DM * DM;
    u16* qb  = Wob + (size_t)DM * DM;
    u16* vb  = qb + (size_t)MM * DM;
    u16* gb  = vb + (size_t)MM * DM;
    float* ebuf  = (float*)(gb + (size_t)MM * DM);   // BB*CC2*DM f32
    float* carry = ebuf + (size_t)BB * CC2 * DM;
    u16* yfin = xb;

    // 1) fp32 -> bf16, single launch
    cvt_all<<<(XF4 + 4 * WF4 + 255) / 256, 256, 0, stream>>>(x, Wq, Wv, Wg, Wo, xb);

    // 2) fused q/v/g projection (N=3072 concat) + chunk-ends for v
    dim3 gq(MM / 256, 3 * DM / 256);
    gemm_qvg<<<gq, 512, 0, stream>>>(xb, Wqb, qb, vb, gb, beta, ebuf);

    // 3) retention scan carries + fused LN + SiLU gate (barrier-free)
    scan_carry<<<(BB * DM) / 256, 256, 0, stream>>>(ebuf, beta, carry);
    dim3 gf(CC2 / 4, BB);
    scan_ln_gate<<<gf, 256, 0, stream>>>(vb, qb, gb, carry, beta, gamma, lnb, yfin);

    // 4) output projection (fp32 out)
    dim3 go(MM / 256, DM / 256);
    gemm_out<<<go, 512, 0, stream>>>(yfin, Wob, (float*)d_out);
}

// Round 11
// 312.983 us; speedup vs baseline: 1.0861x; 1.0300x over previous
//
#include <hip/hip_runtime.h>

// Problem constants (MultiScaleRetention: B=4, L=4096, D=1024, H=16, DH=64)
#define BB 4
#define LL 4096
#define DM 1024
#define NH 16
#define MM (BB * LL)   // 16384 rows
#define CC2 256        // scan chunks per sequence
#define LC2 16         // chunk length (CC2*LC2 == LL)

// GEMM geometry: 256x256 tile, BK=64, 8 waves (2Mx4N), 1-barrier-per-tile
// counted-lgkm interleave schedule.
#define BKT 64
#define NKT (DM / BKT)   // 16 K-tiles

typedef unsigned short u16;
typedef float f32x4 __attribute__((ext_vector_type(4)));
typedef int i32x4 __attribute__((ext_vector_type(4)));
typedef __bf16 mfma_in __attribute__((ext_vector_type(8)));

__device__ __forceinline__ u16 f2bf(float f) {
    unsigned u = __float_as_uint(f);
    u += 0x7FFFu + ((u >> 16) & 1u);   // RNE
    return (u16)(u >> 16);
}
__device__ __forceinline__ float bf2f(u16 u) {
    return __uint_as_float(((unsigned)u) << 16);
}

// async global->LDS, 16B per lane; LDS dest = wave-uniform base + lane*16
__device__ __forceinline__ void gld_lds16(const u16* g, u16* l) {
    __builtin_amdgcn_global_load_lds(
        (const __attribute__((address_space(1))) void*)g,
        (__attribute__((address_space(3))) void*)l,
        16, 0, 0);
}

// Inline-asm ds_read_b128: invisible to the compiler's waitcnt tracking, so
// no hidden vmcnt(0)/lgkmcnt(0) drains get inserted. Completion is enforced
// by our explicit counted lgkmcnt + sched_barrier(0) (DS ops complete
// in-order per wave, so counted waits are deterministic).
__device__ __forceinline__ mfma_in ds_read128(const u16* p) {
    i32x4 r;
    unsigned off = (unsigned)(size_t)(const __attribute__((address_space(3))) u16*)p;
    asm volatile("ds_read_b128 %0, %1" : "=v"(r) : "v"(off));
    return __builtin_bit_cast(mfma_in, r);
}

// ---------------------------------------------------------------- conversions
#define XF4 (MM * DM / 4)
#define WF4 (DM * DM / 4)
__global__ __launch_bounds__(256)
void cvt_all(const float* __restrict__ x,
             const float* __restrict__ w0, const float* __restrict__ w1,
             const float* __restrict__ w2, const float* __restrict__ w3,
             u16* __restrict__ dst) {
    int i = blockIdx.x * 256 + threadIdx.x;
    const float* src;
    int si;
    if (i < XF4) { src = x; si = i; }
    else {
        int j = i - XF4;
        int w = j >> 18;            // WF4 == 2^18
        si = j & (WF4 - 1);
        src = (w == 0) ? w0 : (w == 1) ? w1 : (w == 2) ? w2 : w3;
    }
    float4 f = ((const float4*)src)[si];
    ushort4 o;
    o.x = f2bf(f.x); o.y = f2bf(f.y); o.z = f2bf(f.z); o.w = f2bf(f.w);
    ((ushort4*)dst)[i] = o;
}

// ---------------------------------------------------------------- 256^2 GEMM
// LDS layout per 256x64 K-tile buffer: row = 64 u16 (8 chunks of 16B),
// chunk at (row, logical c) stored at phys = c ^ (row&7) (XOR bank swizzle).
// Staging: swizzle pre-folded into the GLOBAL source address (linear LDS dest).
// Fragment read: row r, k-step s, logical chunk 4s+quad -> phys (4s+quad)^(r&7).
//
// Proven config (r6/r10): mfma(a,b), scalar-store epilogue, split staging
// (A at tile start, B at ~60%), linear block mapping, dead-last-stage skip.
// Known-dead-end ledger: mfma(b,a)+vec epilogue (+11us, r4/r5); XCD swizzle
// (FETCH 78->203MB, r8); B-direct-global pipe-split (reg overflow crash, r9);
// wave-per-chunk ln_gate (TLP loss, r10).
//
// Tile schedule (1 barrier/tile, counted lgkm interleave; DS in-order/wave):
//   issue G1 aLs0(4) G2 bLs0(2) G3 aHs0(4) | stage A(k+1) 4x gld
//   lgkm(4)  -> Q0s0   (G1,G2 done; G3<=4 out)
//   issue G4 bHs0(2); lgkm(2) -> Q1s0      (G3 done; G4<=2)
//   issue G5 aLs1(4); lgkm(4) -> Q2s0,Q3s0 (G4 done; G5<=4)
//   issue G6 bLs1(2) G7 aHs1(4) | stage B(k+1) 4x gld
//   lgkm(4)  -> Q0s1   (G5,G6 done; G7<=4)
//   issue G8 bHs1(2); lgkm(2) -> Q1s1      (G7 done; G8<=2)
//   lgkm(0)  -> Q2s1,Q3s1
//   vmcnt(0); s_barrier      // staged tile k+1 landed+visible; WAR safe

template<int IOFF, int JOFF>
__device__ __forceinline__ void mfma8(const mfma_in (&a)[4], const mfma_in (&b)[2],
                                      f32x4 (&acc)[8][4]) {
#pragma unroll
    for (int i = 0; i < 4; i++)
#pragma unroll
        for (int j = 0; j < 2; j++)
            acc[IOFF + i][JOFF + j] = __builtin_amdgcn_mfma_f32_16x16x32_bf16(
                a[i], b[j], acc[IOFF + i][JOFF + j], 0, 0, 0);
}

#define WAITL(n) do { \
    asm volatile("s_waitcnt lgkmcnt(" #n ")"); \
    __builtin_amdgcn_sched_barrier(0); \
} while (0)

__device__ __forceinline__ void mainloop256(
    const u16* __restrict__ A, const u16* __restrict__ B,
    int mBlk, int nBlk,
    u16 (*__restrict__ As)[256 * 64], u16 (*__restrict__ Bs)[256 * 64],
    f32x4 (&acc)[8][4]) {
    const int tid  = threadIdx.x;
    const int wave = tid >> 6;
    const int lane = tid & 63;
    const int quad = lane >> 4;
    const int l16  = lane & 15;
    const int wm   = (wave >> 2) * 128;   // wave-row: 0..1 -> A half
    const int wn   = (wave & 3) * 64;     // wave-col: 0..3

    // staging addressing (swizzle folded into global source)
    const int sRow = wave * 8 + (lane >> 3);
    const int sCol = ((lane & 7) ^ (lane >> 3)) * 8;
    const u16* gA = A + (size_t)(mBlk + sRow) * DM + sCol;
    const u16* gB = B + (size_t)(nBlk + sRow) * DM + sCol;
    const int ldsW = wave * 8 * 64;       // wave's element offset within a 64-row segment

    // fragment read offsets
    int rA[8], rB[4];
#pragma unroll
    for (int i = 0; i < 8; i++) rA[i] = (wm + i * 16 + l16) * 64;
#pragma unroll
    for (int j = 0; j < 4; j++) rB[j] = (wn + j * 16 + l16) * 64;
    const int c0 = ((quad    ) ^ (l16 & 7)) * 8;
    const int c1 = ((quad + 4) ^ (l16 & 7)) * 8;

    // stage one full 256x64 tile (4x gld_lds per wave), rows in 64-row segments
#define STG4_A(dst, t) do { \
    const int kk_ = (t) * BKT; \
    gld_lds16(gA + kk_,                    (dst) + ldsW); \
    gld_lds16(gA + (size_t) 64 * DM + kk_, (dst) +  64 * 64 + ldsW); \
    gld_lds16(gA + (size_t)128 * DM + kk_, (dst) + 128 * 64 + ldsW); \
    gld_lds16(gA + (size_t)192 * DM + kk_, (dst) + 192 * 64 + ldsW); \
} while (0)
#define STG4_B(dst, t) do { \
    const int kk_ = (t) * BKT; \
    gld_lds16(gB + kk_,                    (dst) + ldsW); \
    gld_lds16(gB + (size_t) 64 * DM + kk_, (dst) +  64 * 64 + ldsW); \
    gld_lds16(gB + (size_t)128 * DM + kk_, (dst) + 128 * 64 + ldsW); \
    gld_lds16(gB + (size_t)192 * DM + kk_, (dst) + 192 * 64 + ldsW); \
} while (0)
#define RDA(dst, idx, cc) (dst) = ds_read128(curA + rA[idx] + (cc))
#define RDB(dst, idx, cc) (dst) = ds_read128(curB + rB[idx] + (cc))

    mfma_in aLs0[4], aHs0[4], bLs0[2], bHs0[2];
    mfma_in aLs1[4], aHs1[4], bLs1[2], bHs1[2];

    // prologue: stage tile 0 into buf0, drain, publish
    STG4_A(As[0], 0);
    STG4_B(Bs[0], 0);
    asm volatile("s_waitcnt vmcnt(0)");
    __builtin_amdgcn_s_barrier();

#pragma unroll 1
    for (int kt = 0; kt < NKT; ++kt) {
        const int cur = kt & 1, nxt = cur ^ 1;
        const u16* curA = As[cur];
        const u16* curB = Bs[cur];
        const bool pre = (kt + 1 < NKT);   // no dead stage on the last tile

        // G1 aL s0, G2 bL s0, G3 aH s0  (out=10)
#pragma unroll
        for (int i = 0; i < 4; i++) RDA(aLs0[i], i, c0);
#pragma unroll
        for (int j = 0; j < 2; j++) RDB(bLs0[j], j, c0);
#pragma unroll
        for (int i = 0; i < 4; i++) RDA(aHs0[i], i + 4, c0);
        if (pre) STG4_A(As[nxt], kt + 1);
        __builtin_amdgcn_sched_barrier(0);

        WAITL(4);                      // G1,G2 done
        __builtin_amdgcn_s_setprio(1);
        mfma8<0, 0>(aLs0, bLs0, acc);  // Q0s0
        __builtin_amdgcn_s_setprio(0);

#pragma unroll
        for (int j = 0; j < 2; j++) RDB(bHs0[j], j + 2, c0);   // G4 (out<=6)
        WAITL(2);                      // G3 done
        __builtin_amdgcn_s_setprio(1);
        mfma8<4, 0>(aHs0, bLs0, acc);  // Q1s0
        __builtin_amdgcn_s_setprio(0);

#pragma unroll
        for (int i = 0; i < 4; i++) RDA(aLs1[i], i, c1);       // G5 (out<=6)
        WAITL(4);                      // G4 done
        __builtin_amdgcn_s_setprio(1);
        mfma8<0, 2>(aLs0, bHs0, acc);  // Q2s0
        mfma8<4, 2>(aHs0, bHs0, acc);  // Q3s0
        __builtin_amdgcn_s_setprio(0);

#pragma unroll
        for (int j = 0; j < 2; j++) RDB(bLs1[j], j, c1);       // G6
#pragma unroll
        for (int i = 0; i < 4; i++) RDA(aHs1[i], i + 4, c1);   // G7 (out<=10)
        if (pre) STG4_B(Bs[nxt], kt + 1);
        __builtin_amdgcn_sched_barrier(0);

        WAITL(4);                      // G5,G6 done
        __builtin_amdgcn_s_setprio(1);
        mfma8<0, 0>(aLs1, bLs1, acc);  // Q0s1
        __builtin_amdgcn_s_setprio(0);

#pragma unroll
        for (int j = 0; j < 2; j++) RDB(bHs1[j], j + 2, c1);   // G8 (out<=6)
        WAITL(2);                      // G7 done
        __builtin_amdgcn_s_setprio(1);
        mfma8<4, 0>(aHs1, bLs1, acc);  // Q1s1
        __builtin_amdgcn_s_setprio(0);

        WAITL(0);                      // G8 done; all tile-k reads drained
        __builtin_amdgcn_s_setprio(1);
        mfma8<0, 2>(aLs1, bHs1, acc);  // Q2s1
        mfma8<4, 2>(aHs1, bHs1, acc);  // Q3s1
        __builtin_amdgcn_s_setprio(0);

        // publish tile k+1 (RAW) + protect bufs for next tile's stages (WAR)
        __builtin_amdgcn_sched_barrier(0);
        asm volatile("s_waitcnt vmcnt(0)");
        __builtin_amdgcn_sched_barrier(0);
        __builtin_amdgcn_s_barrier();
    }
#undef STG4_A
#undef STG4_B
#undef RDA
#undef RDB
}

// fused q/v/g projection: B = concatenated 3072x1024 weights; 3 bf16 outputs.
// v-region blocks also emit retention chunk-ends (ebuf) from the f32 accs.
__global__ __launch_bounds__(512, 2)
void gemm_qvg(const u16* __restrict__ A, const u16* __restrict__ B,
              u16* __restrict__ oq, u16* __restrict__ ov, u16* __restrict__ og,
              const float* __restrict__ beta, float* __restrict__ ebuf) {
    __shared__ __align__(16) u16 As[2][256 * 64];
    __shared__ __align__(16) u16 Bs[2][256 * 64];
    const int mBlk = blockIdx.x * 256;     // linear mapping
    const int nBlk = blockIdx.y * 256;

    f32x4 acc[8][4] = {};
    mainloop256(A, B, mBlk, nBlk, As, Bs, acc);

    const int tid  = threadIdx.x;
    const int wave = tid >> 6;
    const int lane = tid & 63;
    const int quad = lane >> 4;
    const int l16  = lane & 15;
    const int wm   = (wave >> 2) * 128;
    const int wn   = (wave & 3) * 64;

    u16* outs[3] = {oq, ov, og};
    u16* O = outs[nBlk >> 10];
    const int nIn = nBlk & 1023;
#pragma unroll
    for (int i = 0; i < 8; i++) {
        int row0 = mBlk + wm + i * 16 + quad * 4;
#pragma unroll
        for (int j = 0; j < 4; j++) {
            int col = nIn + wn + j * 16 + l16;
#pragma unroll
            for (int r = 0; r < 4; r++)
                O[(size_t)(row0 + r) * DM + col] = f2bf(acc[i][j][r]);
        }
    }

    if ((nBlk >> 10) == 1) {
        // fused chunk-ends for the v region (f32-accurate, pre-bf16-rounding)
        const int rowB = mBlk + wm;            // 256-row tile never straddles a seq
        const int b    = rowB >> 12;
        const int cB   = (rowB & 4095) >> 4;   // chunk of i=0
#pragma unroll
        for (int j = 0; j < 4; j++) {
            int col = nIn + wn + j * 16 + l16;
            float lam  = 1.0f / (1.0f + __expf(-beta[col >> 6]));
            float lam2 = lam * lam, lam4 = lam2 * lam2, lam8 = lam4 * lam4;
            float w = quad == 0 ? lam4 * lam8 : quad == 1 ? lam8
                    : quad == 2 ? lam4 : 1.0f;
#pragma unroll
            for (int i = 0; i < 8; i++) {
                f32x4 a = acc[i][j];
                float p = ((a[0] * lam + a[1]) * lam + a[2]) * lam + a[3];
                float v = p * w;
                v += __shfl_xor(v, 16);
                v += __shfl_xor(v, 32);
                if (quad == 0)
                    ebuf[((size_t)b * CC2 + (cB + i)) * DM + col] = v;
            }
        }
    }
}

// output projection: C (f32) = A @ B^T
__global__ __launch_bounds__(512, 2)
void gemm_out(const u16* __restrict__ A, const u16* __restrict__ B,
              float* __restrict__ C) {
    __shared__ __align__(16) u16 As[2][256 * 64];
    __shared__ __align__(16) u16 Bs[2][256 * 64];
    const int mBlk = blockIdx.x * 256;
    const int nBlk = blockIdx.y * 256;

    f32x4 acc[8][4] = {};
    mainloop256(A, B, mBlk, nBlk, As, Bs, acc);

    const int tid  = threadIdx.x;
    const int wave = tid >> 6;
    const int lane = tid & 63;
    const int quad = lane >> 4;
    const int l16  = lane & 15;
    const int wm   = (wave >> 2) * 128;
    const int wn   = (wave & 3) * 64;

#pragma unroll
    for (int i = 0; i < 8; i++) {
        int row0 = mBlk + wm + i * 16 + quad * 4;
#pragma unroll
        for (int j = 0; j < 4; j++) {
            int col = nBlk + wn + j * 16 + l16;
#pragma unroll
            for (int r = 0; r < 4; r++)
                C[(size_t)(row0 + r) * DM + col] = acc[i][j][r];
        }
    }
}

// ---------------------------------------------------------------- scan phase B
__global__ __launch_bounds__(256)
void scan_carry(const float* __restrict__ ebuf, const float* __restrict__ beta,
                float* __restrict__ carry) {
    int ch = blockIdx.x * 256 + threadIdx.x;  // 0..BB*DM-1
    int b = ch >> 10, d = ch & 1023;
    int h = d >> 6;
    float lam = 1.0f / (1.0f + __expf(-beta[h]));
    float lamC = lam;
    for (int i = 0; i < 4; i++) lamC *= lamC;  // lam^16
    float cur = 0.0f;
#pragma unroll 8
    for (int c = 0; c < CC2; c++) {
        size_t idx = ((size_t)b * CC2 + c) * DM + d;
        carry[idx] = cur;
        cur = lamC * cur + ebuf[idx];
    }
}

// ---------------------------------------------------------------- scan phase C:
// seeded re-scan + y=q*state + LayerNorm + SiLU gate -> bf16.
// Block-per-chunk (r6 form, PROVEN): 1024 blocks x 4 waves = 16 waves/CU.
// r10's wave-per-chunk variant (no barriers) was +11us: only 4 waves/CU,
// not enough TLP to hide HBM latency. Barriers are cheap; waves are not.
__global__ __launch_bounds__(256)
void scan_ln_gate(const u16* __restrict__ v, const u16* __restrict__ q,
                  const u16* __restrict__ g, const float* __restrict__ carry,
                  const float* __restrict__ beta, const float* __restrict__ gamma,
                  const float* __restrict__ lnb, u16* __restrict__ out) {
    __shared__ float red[2][8];
    const int t = threadIdx.x;
    const int c = blockIdx.x, b = blockIdx.y;
    const int wave = t >> 6, lane = t & 63;
    const int d0 = t * 4;
    const int h = d0 >> 6;
    float lam = 1.0f / (1.0f + __expf(-beta[h]));
    float4 gm = ((const float4*)gamma)[t];
    float4 bt = ((const float4*)lnb)[t];
    float4 cr = *(const float4*)(carry + ((size_t)b * CC2 + c) * DM + d0);
    float s0 = cr.x, s1 = cr.y, s2 = cr.z, s3 = cr.w;
    size_t base = ((size_t)b * LL + (size_t)c * LC2) * DM + d0;

    for (int i = 0; i < LC2; i++) {
        ushort4 v4 = *(const ushort4*)(v + base);
        ushort4 q4 = *(const ushort4*)(q + base);
        ushort4 g4 = *(const ushort4*)(g + base);
        s0 = lam * s0 + bf2f(v4.x);
        s1 = lam * s1 + bf2f(v4.y);
        s2 = lam * s2 + bf2f(v4.z);
        s3 = lam * s3 + bf2f(v4.w);
        float y0 = bf2f(q4.x) * s0, y1 = bf2f(q4.y) * s1;
        float y2 = bf2f(q4.z) * s2, y3 = bf2f(q4.w) * s3;
        float sum = y0 + y1 + y2 + y3;
        float sq  = y0 * y0 + y1 * y1 + y2 * y2 + y3 * y3;
#pragma unroll
        for (int off = 32; off > 0; off >>= 1) {
            sum += __shfl_xor(sum, off);
            sq  += __shfl_xor(sq, off);
        }
        int p = i & 1;
        if (lane == 0) { red[p][wave] = sum; red[p][4 + wave] = sq; }
        __syncthreads();
        float ts = red[p][0] + red[p][1] + red[p][2] + red[p][3];
        float tq = red[p][4] + red[p][5] + red[p][6] + red[p][7];
        float mu  = ts * (1.0f / DM);
        float inv = rsqrtf(tq * (1.0f / DM) - mu * mu + 1e-5f);

        float gv0 = bf2f(g4.x), gv1 = bf2f(g4.y), gv2 = bf2f(g4.z), gv3 = bf2f(g4.w);
        float x0 = ((y0 - mu) * inv * gm.x + bt.x) * (gv0 / (1.0f + __expf(-gv0)));
        float x1 = ((y1 - mu) * inv * gm.y + bt.y) * (gv1 / (1.0f + __expf(-gv1)));
        float x2 = ((y2 - mu) * inv * gm.z + bt.z) * (gv2 / (1.0f + __expf(-gv2)));
        float x3 = ((y3 - mu) * inv * gm.w + bt.w) * (gv3 / (1.0f + __expf(-gv3)));
        ushort4 o;
        o.x = f2bf(x0); o.y = f2bf(x1); o.z = f2bf(x2); o.w = f2bf(x3);
        *(ushort4*)(out + base) = o;
        base += DM;
    }
}

// ---------------------------------------------------------------- launcher
extern "C" void kernel_launch(void* const* d_in, const int* in_sizes, int n_in,
                              void* d_out, int out_size, void* d_ws, size_t ws_size,
                              hipStream_t stream) {
    const float* x     = (const float*)d_in[0];
    const float* Wq    = (const float*)d_in[1];
    const float* Wv    = (const float*)d_in[2];
    const float* Wg    = (const float*)d_in[3];
    const float* Wo    = (const float*)d_in[4];
    const float* beta  = (const float*)d_in[5];
    const float* gamma = (const float*)d_in[6];
    const float* lnb   = (const float*)d_in[7];

    // workspace layout (bf16 elements) — xb..Wob contiguous for cvt_all
    u16* xb  = (u16*)d_ws;                    // reused as y_final
    u16* Wqb = xb + (size_t)MM * DM;          // Wq,Wv,Wg concat = 3072x1024
    u16* Wob = Wqb + (size_t)3 * DM * DM;
    u16* qb  = Wob + (size_t)DM * DM;
    u16* vb  = qb + (size_t)MM * DM;
    u16* gb  = vb + (size_t)MM * DM;
    float* ebuf  = (float*)(gb + (size_t)MM * DM);   // BB*CC2*DM f32
    float* carry = ebuf + (size_t)BB * CC2 * DM;
    u16* yfin = xb;

    // 1) fp32 -> bf16, single launch
    cvt_all<<<(XF4 + 4 * WF4 + 255) / 256, 256, 0, stream>>>(x, Wq, Wv, Wg, Wo, xb);

    // 2) fused q/v/g projection (N=3072 concat) + chunk-ends for v
    dim3 gq(MM / 256, 3 * DM / 256);
    gemm_qvg<<<gq, 512, 0, stream>>>(xb, Wqb, qb, vb, gb, beta, ebuf);

    // 3) retention scan carries + fused LN + SiLU gate (block-per-chunk)
    scan_carry<<<(BB * DM) / 256, 256, 0, stream>>>(ebuf, beta, carry);
    dim3 gf(CC2, BB);
    scan_ln_gate<<<gf, 256, 0, stream>>>(vb, qb, gb, carry, beta, gamma, lnb, yfin);

    // 4) output projection (fp32 out)
    dim3 go(MM / 256, DM / 256);
    gemm_out<<<go, 512, 0, stream>>>(yfin, Wob, (float*)d_out);
}